// Round 7
// baseline (669.436 us; speedup 1.0000x reference)
//
#include <hip/hip_runtime.h>
#include <math.h>

typedef unsigned short ushort_t;

// ---------- helpers ----------

__device__ inline unsigned fenc(float f) {
    unsigned u = __float_as_uint(f);
    return (u & 0x80000000u) ? ~u : (u | 0x80000000u);
}
__device__ inline float fdec(unsigned u) {
    return __uint_as_float((u & 0x80000000u) ? (u ^ 0x80000000u) : ~u);
}

__device__ inline float wrsum(float v) {
    #pragma unroll
    for (int m = 32; m; m >>= 1) v += __shfl_xor(v, m, 64);
    return v;
}
__device__ inline float wrmax(float v) {
    #pragma unroll
    for (int m = 32; m; m >>= 1) v = fmaxf(v, __shfl_xor(v, m, 64));
    return v;
}
__device__ inline float lrelu(float x) { return x > 0.f ? x : 0.2f * x; }

__device__ inline ushort_t f2bf(float f) {
    unsigned u = __float_as_uint(f);
    u += 0x7FFFu + ((u >> 16) & 1u);      // round-to-nearest-even
    return (ushort_t)(u >> 16);
}
__device__ inline float bflo(unsigned u) { return __uint_as_float(u << 16); }
__device__ inline float bfhi(unsigned u) { return __uint_as_float(u & 0xFFFF0000u); }

// ---------- GEMM 1 + fused scores1.  h1b[n][dd][h] permuted bf16 layout ----------
__global__ __launch_bounds__(256) void gemm1_kernel(const float* __restrict__ x,
                                                    const float* __restrict__ W,
                                                    const float* __restrict__ a_src,
                                                    const float* __restrict__ a_dst,
                                                    ushort_t* __restrict__ h1b,
                                                    float* __restrict__ ssrc,
                                                    float* __restrict__ sdst, int N) {
    __shared__ float xs[16 * 128];      // staged x tile (reused as partial buf)
    __shared__ float ss[16 * 257];      // acc transpose for score reduction
    int base = blockIdx.x * 16;
    int tid = threadIdx.x;
    const float4* xv = (const float4*)(x + (size_t)base * 128);
    float4* xsv = (float4*)xs;
    #pragma unroll
    for (int i = tid; i < 512; i += 256) {
        int n = base + (i >> 5);
        xsv[i] = (n < N) ? xv[i] : make_float4(0.f, 0.f, 0.f, 0.f);
    }
    __syncthreads();
    float acc[16];
    #pragma unroll
    for (int j = 0; j < 16; j++) acc[j] = 0.f;
    for (int k = 0; k < 128; k += 4) {
        float w0 = W[k * 256 + tid];
        float w1 = W[(k + 1) * 256 + tid];
        float w2 = W[(k + 2) * 256 + tid];
        float w3 = W[(k + 3) * 256 + tid];
        #pragma unroll
        for (int j = 0; j < 16; j++) {
            float4 xj = *(const float4*)(xs + j * 128 + k);
            acc[j] += xj.x * w0 + xj.y * w1 + xj.z * w2 + xj.w * w3;
        }
    }
    int dd = tid & 63, hh = tid >> 6;
    #pragma unroll
    for (int j = 0; j < 16; j++) {
        int n = base + j;
        if (n < N) h1b[(size_t)n * 256 + dd * 4 + hh] = f2bf(acc[j]);
    }
    // ---- scores via LDS transpose + partial sums ----
    #pragma unroll
    for (int j = 0; j < 16; j++) ss[j * 257 + tid] = acc[j];
    __syncthreads();
    int j = tid & 15, hh2 = (tid >> 4) & 3, which = (tid >> 6) & 1, half = tid >> 7;
    const float* av = which ? a_dst : a_src;
    int cbase = hh2 * 64 + half * 32;
    float sum = 0.f;
    #pragma unroll
    for (int i = 0; i < 32; i++) sum += ss[j * 257 + cbase + i] * av[cbase + i];
    xs[tid] = sum;            // xs reused as partial buffer
    __syncthreads();
    if (half == 0) {
        float tot = sum + xs[tid + 128];
        int n = base + j;
        if (n < N) (which ? sdst : ssrc)[n * 4 + hh2] = tot;
    }
}

// ---------- GEMM 2 + fused scores2: h2b[N,64] bf16 = x2[N,256] @ W2[256,64] ----------
__global__ __launch_bounds__(256) void gemm2_kernel(const float* __restrict__ x2,
                                                    const float* __restrict__ W,
                                                    const float* __restrict__ a_src,
                                                    const float* __restrict__ a_dst,
                                                    ushort_t* __restrict__ h2b,
                                                    float* __restrict__ ssrc,
                                                    float* __restrict__ sdst, int N) {
    __shared__ float xs[16 * 256];
    int base = blockIdx.x * 16;
    int tid = threadIdx.x;
    const float4* xv = (const float4*)(x2 + (size_t)base * 256);
    float4* xsv = (float4*)xs;
    #pragma unroll
    for (int i = tid; i < 1024; i += 256) {
        int n = base + (i >> 6);
        xsv[i] = (n < N) ? xv[i] : make_float4(0.f, 0.f, 0.f, 0.f);
    }
    __syncthreads();
    int c = tid & 63, sub = tid >> 6;
    float acc[4] = {0.f, 0.f, 0.f, 0.f};
    for (int k = 0; k < 256; k += 4) {
        float w0 = W[k * 64 + c];
        float w1 = W[(k + 1) * 64 + c];
        float w2 = W[(k + 2) * 64 + c];
        float w3 = W[(k + 3) * 64 + c];
        #pragma unroll
        for (int j = 0; j < 4; j++) {
            float4 xj = *(const float4*)(xs + (sub + 4 * j) * 256 + k);
            acc[j] += xj.x * w0 + xj.y * w1 + xj.z * w2 + xj.w * w3;
        }
    }
    float as = a_src[c], ad = a_dst[c];
    #pragma unroll
    for (int j = 0; j < 4; j++) {
        int n = base + sub + 4 * j;
        if (n < N) h2b[(size_t)n * 64 + c] = f2bf(acc[j]);
        float ps = wrsum(acc[j] * as);
        float pd = wrsum(acc[j] * ad);
        if (c == 0 && n < N) { ssrc[n] = ps; sdst[n] = pd; }
    }
}

// ---------- CSR build ----------
__global__ __launch_bounds__(256) void hist_kernel(const int* __restrict__ ei,
                                                   int* __restrict__ deg, int E, int Etot) {
    int i = blockIdx.x * 256 + threadIdx.x;
    if (i >= Etot) return;
    int d = (i < E) ? ei[E + i] : (i - E);
    atomicAdd(&deg[d], 1);
}

__global__ __launch_bounds__(256) void chunksum_kernel(const int* __restrict__ deg,
                                                       int* __restrict__ csum, int M) {
    __shared__ int sm[256];
    int t = blockIdx.x * 256 + threadIdx.x;
    sm[threadIdx.x] = (t < M) ? deg[t] : 0;
    __syncthreads();
    for (int off = 128; off > 0; off >>= 1) {
        if (threadIdx.x < off) sm[threadIdx.x] += sm[threadIdx.x + off];
        __syncthreads();
    }
    if (threadIdx.x == 0) csum[blockIdx.x] = sm[0];
}

__global__ __launch_bounds__(256) void scanchunks_kernel(const int* __restrict__ csum,
                                                         int* __restrict__ coffset, int nchunks) {
    __shared__ int sm[256];
    int v = (threadIdx.x < nchunks) ? csum[threadIdx.x] : 0;
    sm[threadIdx.x] = v;
    __syncthreads();
    for (int off = 1; off < 256; off <<= 1) {
        int a = (threadIdx.x >= off) ? sm[threadIdx.x - off] : 0;
        __syncthreads();
        sm[threadIdx.x] += a;
        __syncthreads();
    }
    coffset[threadIdx.x] = sm[threadIdx.x] - v;
}

__global__ __launch_bounds__(256) void rowptr_kernel(const int* __restrict__ deg,
                                                     const int* __restrict__ coffset,
                                                     int* __restrict__ rowptr,
                                                     int* __restrict__ cursor, int M, int N) {
    __shared__ int sm[256];
    int t = blockIdx.x * 256 + threadIdx.x;
    int v = (t < M) ? deg[t] : 0;
    sm[threadIdx.x] = v;
    __syncthreads();
    for (int off = 1; off < 256; off <<= 1) {
        int a = (threadIdx.x >= off) ? sm[threadIdx.x - off] : 0;
        __syncthreads();
        sm[threadIdx.x] += a;
        __syncthreads();
    }
    if (t < M) {
        int rp = coffset[blockIdx.x] + sm[threadIdx.x] - v;
        rowptr[t] = rp;
        if (t < N) cursor[t] = rp;
    }
}

__global__ __launch_bounds__(256) void scatter_kernel(const int* __restrict__ ei,
                                                      int* __restrict__ cursor,
                                                      int* __restrict__ srcbuf, int E, int Etot) {
    int i = blockIdx.x * 256 + threadIdx.x;
    if (i >= Etot) return;
    int s, d;
    if (i < E) { s = ei[i]; d = ei[E + i]; } else { s = d = i - E; }
    int pos = atomicAdd(&cursor[d], 1);
    srcbuf[pos] = s;
}

// ---------- prep1: per-row max+denom, writes NORMALIZED weights to wbuf4 (CSR order) ----------
__global__ __launch_bounds__(256) void prep1_kernel(const int* __restrict__ rowptr,
                                                    const int* __restrict__ srcbuf,
                                                    const float* __restrict__ ssrc,
                                                    const float* __restrict__ sdst,
                                                    float* __restrict__ wbuf4, int N) {
    int lane = threadIdx.x & 63, w = threadIdx.x >> 6;
    int d = blockIdx.x * 4 + w;
    if (d >= N) return;
    int row = rowptr[d], end = rowptr[d + 1];
    float4 sd = *(const float4*)(sdst + d * 4);
    float4 mx = make_float4(-INFINITY, -INFINITY, -INFINITY, -INFINITY);
    for (int base = row; base < end; base += 64) {
        bool valid = base + lane < end;
        int s = valid ? srcbuf[base + lane] : 0;
        float4 ssv = *(const float4*)(ssrc + s * 4);
        if (valid) {
            mx.x = fmaxf(mx.x, ssv.x); mx.y = fmaxf(mx.y, ssv.y);
            mx.z = fmaxf(mx.z, ssv.z); mx.w = fmaxf(mx.w, ssv.w);
        }
    }
    mx.x = wrmax(mx.x); mx.y = wrmax(mx.y); mx.z = wrmax(mx.z); mx.w = wrmax(mx.w);
    float4 md = make_float4(lrelu(mx.x + sd.x), lrelu(mx.y + sd.y),
                            lrelu(mx.z + sd.z), lrelu(mx.w + sd.w));
    float4 ls = make_float4(0.f, 0.f, 0.f, 0.f);
    float4 wt0 = make_float4(0.f, 0.f, 0.f, 0.f);
    for (int base = row; base < end; base += 64) {
        bool valid = base + lane < end;
        int s = valid ? srcbuf[base + lane] : 0;
        float4 ssv = *(const float4*)(ssrc + s * 4);
        float4 wt;
        wt.x = valid ? __expf(lrelu(ssv.x + sd.x) - md.x) : 0.f;
        wt.y = valid ? __expf(lrelu(ssv.y + sd.y) - md.y) : 0.f;
        wt.z = valid ? __expf(lrelu(ssv.z + sd.z) - md.z) : 0.f;
        wt.w = valid ? __expf(lrelu(ssv.w + sd.w) - md.w) : 0.f;
        if (base == row) wt0 = wt;
        ls.x += wt.x; ls.y += wt.y; ls.z += wt.z; ls.w += wt.w;
    }
    ls.x = wrsum(ls.x); ls.y = wrsum(ls.y); ls.z = wrsum(ls.z); ls.w = wrsum(ls.w);
    float4 inv = make_float4(1.f / ls.x, 1.f / ls.y, 1.f / ls.z, 1.f / ls.w);
    if (row + lane < end) {
        *(float4*)(wbuf4 + (size_t)(row + lane) * 4) =
            make_float4(wt0.x * inv.x, wt0.y * inv.y, wt0.z * inv.z, wt0.w * inv.w);
    }
    // rare rows with >64 edges: recompute remaining chunks
    for (int base = row + 64; base < end; base += 64) {
        bool valid = base + lane < end;
        int s = valid ? srcbuf[base + lane] : 0;
        float4 ssv = *(const float4*)(ssrc + s * 4);
        if (valid) {
            float4 wt;
            wt.x = __expf(lrelu(ssv.x + sd.x) - md.x) * inv.x;
            wt.y = __expf(lrelu(ssv.y + sd.y) - md.y) * inv.y;
            wt.z = __expf(lrelu(ssv.z + sd.z) - md.z) * inv.z;
            wt.w = __expf(lrelu(ssv.w + sd.w) - md.w) * inv.w;
            *(float4*)(wbuf4 + (size_t)(base + lane) * 4) = wt;
        }
    }
}

// ---------- prep2: per-row max+denom, writes normalized weights to wbuf1 ----------
__global__ __launch_bounds__(256) void prep2_kernel(const int* __restrict__ rowptr,
                                                    const int* __restrict__ srcbuf,
                                                    const float* __restrict__ ssrc,
                                                    const float* __restrict__ sdst,
                                                    float* __restrict__ wbuf1, int N) {
    int lane = threadIdx.x & 63, w = threadIdx.x >> 6;
    int d = blockIdx.x * 4 + w;
    if (d >= N) return;
    int row = rowptr[d], end = rowptr[d + 1];
    float sd = sdst[d];
    float mx = -INFINITY;
    for (int base = row; base < end; base += 64) {
        bool valid = base + lane < end;
        int s = valid ? srcbuf[base + lane] : 0;
        float ssv = ssrc[s];
        if (valid) mx = fmaxf(mx, ssv);
    }
    mx = wrmax(mx);
    float md = lrelu(mx + sd);
    float ls = 0.f, wt0 = 0.f;
    for (int base = row; base < end; base += 64) {
        bool valid = base + lane < end;
        int s = valid ? srcbuf[base + lane] : 0;
        float ssv = ssrc[s];
        float wt = valid ? __expf(lrelu(ssv + sd) - md) : 0.f;
        if (base == row) wt0 = wt;
        ls += wt;
    }
    ls = wrsum(ls);
    float inv = 1.f / ls;
    if (row + lane < end) wbuf1[row + lane] = wt0 * inv;
    for (int base = row + 64; base < end; base += 64) {
        bool valid = base + lane < end;
        int s = valid ? srcbuf[base + lane] : 0;
        float ssv = ssrc[s];
        if (valid) wbuf1[base + lane] = __expf(lrelu(ssv + sd) - md) * inv;
    }
}

// ---------- layer-1 aggregation: coalesced weights, bf16 rows, 2 edges/instr ----------
__global__ __launch_bounds__(256) void agg1_kernel(const int* __restrict__ rowptr,
                                                   const int* __restrict__ srcbuf,
                                                   const float* __restrict__ wbuf4,
                                                   const ushort_t* __restrict__ h1b,
                                                   const float* __restrict__ b1,
                                                   float* __restrict__ x2, int N) {
    __shared__ int    s_sh[4][64];
    __shared__ float4 w_sh[4][64];
    int lane = threadIdx.x & 63, w = threadIdx.x >> 6;
    int eo = lane >> 5, q = lane & 31;   // edge-in-pair, dim-pair index
    int d = blockIdx.x * 4 + w;
    if (d >= N) return;
    int row = rowptr[d], end = rowptr[d + 1];
    float acc8[8];
    #pragma unroll
    for (int i = 0; i < 8; i++) acc8[i] = 0.f;

    for (int base = row; base < end; base += 64) {
        int cnt = min(64, end - base);
        bool valid = lane < cnt;
        int s = valid ? srcbuf[base + lane] : 0;
        float4 wt = *(const float4*)(wbuf4 + (size_t)(base + lane) * 4);  // +64 padded alloc
        if (!valid) wt = make_float4(0.f, 0.f, 0.f, 0.f);
        s_sh[w][lane] = s;
        w_sh[w][lane] = wt;
        // wave-private LDS; lockstep wave, no barrier needed
        int cnt4 = (cnt + 3) & ~3;
        for (int j = 0; j < cnt4; j += 4) {
            int ea = j + eo, eb = j + 2 + eo;
            int sa = s_sh[w][ea], sb = s_sh[w][eb];
            float4 wa = w_sh[w][ea], wb = w_sh[w][eb];
            uint4 ua = *(const uint4*)(h1b + (size_t)sa * 256 + q * 8);
            uint4 ub = *(const uint4*)(h1b + (size_t)sb * 256 + q * 8);
            acc8[0] += wa.x * bflo(ua.x); acc8[1] += wa.y * bfhi(ua.x);
            acc8[2] += wa.z * bflo(ua.y); acc8[3] += wa.w * bfhi(ua.y);
            acc8[4] += wa.x * bflo(ua.z); acc8[5] += wa.y * bfhi(ua.z);
            acc8[6] += wa.z * bflo(ua.w); acc8[7] += wa.w * bfhi(ua.w);
            acc8[0] += wb.x * bflo(ub.x); acc8[1] += wb.y * bfhi(ub.x);
            acc8[2] += wb.z * bflo(ub.y); acc8[3] += wb.w * bfhi(ub.y);
            acc8[4] += wb.x * bflo(ub.z); acc8[5] += wb.y * bfhi(ub.z);
            acc8[6] += wb.z * bflo(ub.w); acc8[7] += wb.w * bfhi(ub.w);
        }
    }
    // combine the two edge-halves (lanes l and l^32 hold same dims)
    #pragma unroll
    for (int i = 0; i < 8; i++) acc8[i] += __shfl_xor(acc8[i], 32, 64);
    if (eo == 0) {
        float* xp = x2 + (size_t)d * 256;
        #pragma unroll
        for (int t = 0; t < 2; t++) {
            int dd = 2 * q + t;
            #pragma unroll
            for (int h = 0; h < 4; h++) {
                float v = acc8[t * 4 + h] + b1[h * 64 + dd];
                v = v > 0.f ? v : __expf(v) - 1.f;   // ELU
                xp[h * 64 + dd] = v;
            }
        }
    }
}

// ---------- layer-2 aggregation: coalesced weights, bf16 rows, 8 edges/instr ----------
__global__ __launch_bounds__(256) void agg2_kernel(const int* __restrict__ rowptr,
                                                   const int* __restrict__ srcbuf,
                                                   const float* __restrict__ wbuf1,
                                                   const ushort_t* __restrict__ h2b,
                                                   const float* __restrict__ b2,
                                                   unsigned* __restrict__ minenc, int N) {
    __shared__ int   s_sh[4][64];
    __shared__ float w_sh[4][64];
    __shared__ float t_sh[4][64];
    int lane = threadIdx.x & 63, w = threadIdx.x >> 6;
    int eo = lane >> 3, q = lane & 7;    // edge-in-group of 8, dim-octet index
    int d = blockIdx.x * 4 + w;
    float out = INFINITY;
    if (d < N) {
        int row = rowptr[d], end = rowptr[d + 1];
        float acc8[8];
        #pragma unroll
        for (int i = 0; i < 8; i++) acc8[i] = 0.f;
        for (int base = row; base < end; base += 64) {
            int cnt = min(64, end - base);
            bool valid = lane < cnt;
            int s = valid ? srcbuf[base + lane] : 0;
            float wt = wbuf1[base + lane];   // +64 padded alloc
            if (!valid) wt = 0.f;
            s_sh[w][lane] = s;
            w_sh[w][lane] = wt;
            int cnt8 = (cnt + 7) & ~7;
            for (int j = 0; j < cnt8; j += 8) {
                int e = j + eo;
                int se = s_sh[w][e];
                float we = w_sh[w][e];
                uint4 u = *(const uint4*)(h2b + (size_t)se * 64 + q * 8);
                acc8[0] += we * bflo(u.x); acc8[1] += we * bfhi(u.x);
                acc8[2] += we * bflo(u.y); acc8[3] += we * bfhi(u.y);
                acc8[4] += we * bflo(u.z); acc8[5] += we * bfhi(u.z);
                acc8[6] += we * bflo(u.w); acc8[7] += we * bfhi(u.w);
            }
        }
        // reduce across the 8 edge-groups (xor masks 8,16,32)
        #pragma unroll
        for (int i = 0; i < 8; i++) {
            acc8[i] += __shfl_xor(acc8[i], 8, 64);
            acc8[i] += __shfl_xor(acc8[i], 16, 64);
            acc8[i] += __shfl_xor(acc8[i], 32, 64);
        }
        if (lane < 8) {
            #pragma unroll
            for (int i = 0; i < 8; i++) t_sh[w][q * 8 + i] = acc8[i];
        }
        float accd = t_sh[w][lane];      // wave-private, lockstep
        out = accd + b2[lane];
    }
    __shared__ float sm[256];
    sm[threadIdx.x] = out;
    __syncthreads();
    if (w == 0) {
        float v = fminf(fminf(sm[lane], sm[64 + lane]), fminf(sm[128 + lane], sm[192 + lane]));
        atomicMin(&minenc[lane], fenc(v));
    }
}

__global__ void decode_kernel(const unsigned* __restrict__ minenc, float* __restrict__ out) {
    int d = threadIdx.x;
    if (d < 64) out[d] = fdec(minenc[d]);
}

// ---------- launch ----------
extern "C" void kernel_launch(void* const* d_in, const int* in_sizes, int n_in,
                              void* d_out, int out_size, void* d_ws, size_t ws_size,
                              hipStream_t stream) {
    const float* x      = (const float*)d_in[0];
    const int*   ei     = (const int*)d_in[1];
    const float* W1     = (const float*)d_in[2];
    const float* a_src1 = (const float*)d_in[3];
    const float* a_dst1 = (const float*)d_in[4];
    const float* b1     = (const float*)d_in[5];
    const float* W2     = (const float*)d_in[6];
    const float* a_src2 = (const float*)d_in[7];
    const float* a_dst2 = (const float*)d_in[8];
    const float* b2     = (const float*)d_in[9];
    float* out = (float*)d_out;

    const int N = in_sizes[0] / 128;
    const int E = in_sizes[1] / 2;
    const int Etot = E + N;
    const int Epad = Etot + 64;            // padded so masked tail reads stay in-bounds
    const int M = N + 1;
    const int nchunks = (M + 255) / 256;   // <= 256 for N <= ~65k

    // workspace layout (4-byte words; N divisible by 4 keeps 16B alignment)
    float* ws = (float*)d_ws;
    ushort_t* h1b = (ushort_t*)ws;                    // N*256 bf16 = N*128 words
    float* x2     = ws + (size_t)N * 128;             // N*256
    ushort_t* h2b = (ushort_t*)(x2 + (size_t)N * 256); // N*64 bf16 = N*32 words
    float* ssrc1  = x2 + (size_t)N * 256 + (size_t)N * 32;  // 4N (16B aligned)
    float* sdst1  = ssrc1 + (size_t)N * 4;            // 4N
    float* wbuf4  = sdst1 + (size_t)N * 4;            // 4*Epad (16B aligned)
    float* wbuf1  = wbuf4 + (size_t)Epad * 4;         // Epad
    float* ssrc2  = wbuf1 + Epad;                     // N
    float* sdst2  = ssrc2 + N;                        // N
    int*   deg    = (int*)(sdst2 + N);                // N+1
    int*   rowptr = deg + M;                          // N+1
    int*   cursor = rowptr + M;                       // N
    int*   csum   = cursor + N;                       // 256
    int*   coff   = csum + 256;                       // 256
    int*   srcbuf = coff + 256;                       // Epad
    unsigned* minenc = (unsigned*)(srcbuf + Epad);    // 64

    hipMemsetAsync(deg, 0, (size_t)M * 4, stream);
    hipMemsetAsync(minenc, 0xFF, 64 * 4, stream);

    int nb16 = (N + 15) / 16;
    int nb4 = (N + 3) / 4;
    gemm1_kernel<<<nb16, 256, 0, stream>>>(x, W1, a_src1, a_dst1, h1b, ssrc1, sdst1, N);

    hist_kernel<<<(Etot + 255) / 256, 256, 0, stream>>>(ei, deg, E, Etot);
    chunksum_kernel<<<nchunks, 256, 0, stream>>>(deg, csum, M);
    scanchunks_kernel<<<1, 256, 0, stream>>>(csum, coff, nchunks);
    rowptr_kernel<<<nchunks, 256, 0, stream>>>(deg, coff, rowptr, cursor, M, N);
    scatter_kernel<<<(Etot + 255) / 256, 256, 0, stream>>>(ei, cursor, srcbuf, E, Etot);

    prep1_kernel<<<nb4, 256, 0, stream>>>(rowptr, srcbuf, ssrc1, sdst1, wbuf4, N);
    agg1_kernel<<<nb4, 256, 0, stream>>>(rowptr, srcbuf, wbuf4, h1b, b1, x2, N);
    gemm2_kernel<<<nb16, 256, 0, stream>>>(x2, W2, a_src2, a_dst2, h2b, ssrc2, sdst2, N);
    prep2_kernel<<<nb4, 256, 0, stream>>>(rowptr, srcbuf, ssrc2, sdst2, wbuf1, N);
    agg2_kernel<<<nb4, 256, 0, stream>>>(rowptr, srcbuf, wbuf1, h2b, b2, minenc, N);
    decode_kernel<<<1, 64, 0, stream>>>(minenc, out);
}

// Round 8
// 462.033 us; speedup vs baseline: 1.4489x; 1.4489x over previous
//
#include <hip/hip_runtime.h>
#include <math.h>

typedef unsigned short ushort_t;

// ---------- helpers ----------

__device__ inline unsigned fenc(float f) {
    unsigned u = __float_as_uint(f);
    return (u & 0x80000000u) ? ~u : (u | 0x80000000u);
}
__device__ inline float fdec(unsigned u) {
    return __uint_as_float((u & 0x80000000u) ? (u ^ 0x80000000u) : ~u);
}

__device__ inline float wrsum(float v) {
    #pragma unroll
    for (int m = 32; m; m >>= 1) v += __shfl_xor(v, m, 64);
    return v;
}
__device__ inline float wrmax(float v) {
    #pragma unroll
    for (int m = 32; m; m >>= 1) v = fmaxf(v, __shfl_xor(v, m, 64));
    return v;
}
__device__ inline float lrelu(float x) { return x > 0.f ? x : 0.2f * x; }

__device__ inline ushort_t f2bf(float f) {
    unsigned u = __float_as_uint(f);
    u += 0x7FFFu + ((u >> 16) & 1u);      // round-to-nearest-even
    return (ushort_t)(u >> 16);
}
__device__ inline float bflo(unsigned u) { return __uint_as_float(u << 16); }
__device__ inline float bfhi(unsigned u) { return __uint_as_float(u & 0xFFFF0000u); }

// ---------- GEMM 1 + fused scores1.  h1b[n][dd][h] permuted bf16 layout ----------
__global__ __launch_bounds__(256) void gemm1_kernel(const float* __restrict__ x,
                                                    const float* __restrict__ W,
                                                    const float* __restrict__ a_src,
                                                    const float* __restrict__ a_dst,
                                                    ushort_t* __restrict__ h1b,
                                                    float* __restrict__ ssrc,
                                                    float* __restrict__ sdst, int N) {
    __shared__ float xs[16 * 128];      // staged x tile (reused as partial buf)
    __shared__ float ss[16 * 257];      // acc transpose for score reduction
    int base = blockIdx.x * 16;
    int tid = threadIdx.x;
    const float4* xv = (const float4*)(x + (size_t)base * 128);
    float4* xsv = (float4*)xs;
    #pragma unroll
    for (int i = tid; i < 512; i += 256) {
        int n = base + (i >> 5);
        xsv[i] = (n < N) ? xv[i] : make_float4(0.f, 0.f, 0.f, 0.f);
    }
    __syncthreads();
    float acc[16];
    #pragma unroll
    for (int j = 0; j < 16; j++) acc[j] = 0.f;
    for (int k = 0; k < 128; k += 4) {
        float w0 = W[k * 256 + tid];
        float w1 = W[(k + 1) * 256 + tid];
        float w2 = W[(k + 2) * 256 + tid];
        float w3 = W[(k + 3) * 256 + tid];
        #pragma unroll
        for (int j = 0; j < 16; j++) {
            float4 xj = *(const float4*)(xs + j * 128 + k);
            acc[j] += xj.x * w0 + xj.y * w1 + xj.z * w2 + xj.w * w3;
        }
    }
    int dd = tid & 63, hh = tid >> 6;
    #pragma unroll
    for (int j = 0; j < 16; j++) {
        int n = base + j;
        if (n < N) h1b[(size_t)n * 256 + dd * 4 + hh] = f2bf(acc[j]);
    }
    // ---- scores via LDS transpose + partial sums ----
    #pragma unroll
    for (int j = 0; j < 16; j++) ss[j * 257 + tid] = acc[j];
    __syncthreads();
    int j = tid & 15, hh2 = (tid >> 4) & 3, which = (tid >> 6) & 1, half = tid >> 7;
    const float* av = which ? a_dst : a_src;
    int cbase = hh2 * 64 + half * 32;
    float sum = 0.f;
    #pragma unroll
    for (int i = 0; i < 32; i++) sum += ss[j * 257 + cbase + i] * av[cbase + i];
    xs[tid] = sum;            // xs reused as partial buffer
    __syncthreads();
    if (half == 0) {
        float tot = sum + xs[tid + 128];
        int n = base + j;
        if (n < N) (which ? sdst : ssrc)[n * 4 + hh2] = tot;
    }
}

// ---------- CSR build ----------
__global__ __launch_bounds__(256) void hist_kernel(const int* __restrict__ ei,
                                                   int* __restrict__ deg, int E, int Etot) {
    int i = blockIdx.x * 256 + threadIdx.x;
    if (i >= Etot) return;
    int d = (i < E) ? ei[E + i] : (i - E);
    atomicAdd(&deg[d], 1);
}

__global__ __launch_bounds__(256) void chunksum_kernel(const int* __restrict__ deg,
                                                       int* __restrict__ csum, int M) {
    __shared__ int sm[256];
    int t = blockIdx.x * 256 + threadIdx.x;
    sm[threadIdx.x] = (t < M) ? deg[t] : 0;
    __syncthreads();
    for (int off = 128; off > 0; off >>= 1) {
        if (threadIdx.x < off) sm[threadIdx.x] += sm[threadIdx.x + off];
        __syncthreads();
    }
    if (threadIdx.x == 0) csum[blockIdx.x] = sm[0];
}

__global__ __launch_bounds__(256) void scanchunks_kernel(const int* __restrict__ csum,
                                                         int* __restrict__ coffset, int nchunks) {
    __shared__ int sm[256];
    int v = (threadIdx.x < nchunks) ? csum[threadIdx.x] : 0;
    sm[threadIdx.x] = v;
    __syncthreads();
    for (int off = 1; off < 256; off <<= 1) {
        int a = (threadIdx.x >= off) ? sm[threadIdx.x - off] : 0;
        __syncthreads();
        sm[threadIdx.x] += a;
        __syncthreads();
    }
    coffset[threadIdx.x] = sm[threadIdx.x] - v;
}

__global__ __launch_bounds__(256) void rowptr_kernel(const int* __restrict__ deg,
                                                     const int* __restrict__ coffset,
                                                     int* __restrict__ rowptr,
                                                     int* __restrict__ cursor, int M, int N) {
    __shared__ int sm[256];
    int t = blockIdx.x * 256 + threadIdx.x;
    int v = (t < M) ? deg[t] : 0;
    sm[threadIdx.x] = v;
    __syncthreads();
    for (int off = 1; off < 256; off <<= 1) {
        int a = (threadIdx.x >= off) ? sm[threadIdx.x - off] : 0;
        __syncthreads();
        sm[threadIdx.x] += a;
        __syncthreads();
    }
    if (t < M) {
        int rp = coffset[blockIdx.x] + sm[threadIdx.x] - v;
        rowptr[t] = rp;
        if (t < N) cursor[t] = rp;
    }
}

__global__ __launch_bounds__(256) void scatter_kernel(const int* __restrict__ ei,
                                                      int* __restrict__ cursor,
                                                      int* __restrict__ srcbuf, int E, int Etot) {
    int i = blockIdx.x * 256 + threadIdx.x;
    if (i >= Etot) return;
    int s, d;
    if (i < E) { s = ei[i]; d = ei[E + i]; } else { s = d = i - E; }
    int pos = atomicAdd(&cursor[d], 1);
    srcbuf[pos] = s;
}

// ---------- va/vb = W2 @ a_src2 / a_dst2 (folded layer-2 score vectors) ----------
__global__ __launch_bounds__(256) void vab_kernel(const float* __restrict__ W2,
                                                  const float* __restrict__ a_src2,
                                                  const float* __restrict__ a_dst2,
                                                  float* __restrict__ va,
                                                  float* __restrict__ vb) {
    int k = threadIdx.x;   // 256 threads = 256 rows of W2
    float sa = 0.f, sb = 0.f;
    #pragma unroll 8
    for (int c = 0; c < 64; c++) {
        float w = W2[k * 64 + c];
        sa += w * a_src2[c];
        sb += w * a_dst2[c];
    }
    va[k] = sa;
    vb[k] = sb;
}

// ---------- layer-1 aggregation: R4 shape, bf16 512B rows, 1 row/instr, inline softmax ----------
// epilogue: x2b (bf16) + layer-2 scores via folded va/vb
__global__ __launch_bounds__(256) void agg1_kernel(const int* __restrict__ rowptr,
                                                   const int* __restrict__ srcbuf,
                                                   const float* __restrict__ ssrc,
                                                   const float* __restrict__ sdst,
                                                   const ushort_t* __restrict__ h1b,
                                                   const float* __restrict__ b1,
                                                   const float* __restrict__ va,
                                                   const float* __restrict__ vb,
                                                   ushort_t* __restrict__ x2b,
                                                   float* __restrict__ ssrc2,
                                                   float* __restrict__ sdst2, int N) {
    __shared__ int    s_sh[4][64];
    __shared__ float4 w_sh[4][64];
    int lane = threadIdx.x & 63, w = threadIdx.x >> 6;
    int d = blockIdx.x * 4 + w;
    if (d >= N) return;
    int row = rowptr[d], end = rowptr[d + 1];
    float4 sd = *(const float4*)(sdst + d * 4);
    float m0 = -INFINITY, m1 = -INFINITY, m2 = -INFINITY, m3 = -INFINITY;
    float l0 = 0.f, l1 = 0.f, l2 = 0.f, l3 = 0.f;
    float a0 = 0.f, a1 = 0.f, a2 = 0.f, a3 = 0.f;

    for (int base = row; base < end; base += 64) {
        int cnt = min(64, end - base);
        bool valid = lane < cnt;
        int s = valid ? srcbuf[base + lane] : 0;
        float4 ssv = *(const float4*)(ssrc + s * 4);
        float e0 = ssv.x + sd.x, e1 = ssv.y + sd.y, e2 = ssv.z + sd.z, e3 = ssv.w + sd.w;
        e0 = lrelu(e0); e1 = lrelu(e1); e2 = lrelu(e2); e3 = lrelu(e3);
        if (!valid) { e0 = e1 = e2 = e3 = -INFINITY; }
        float nm0 = fmaxf(m0, wrmax(e0)), nm1 = fmaxf(m1, wrmax(e1));
        float nm2 = fmaxf(m2, wrmax(e2)), nm3 = fmaxf(m3, wrmax(e3));
        float sc0 = __expf(m0 - nm0), sc1 = __expf(m1 - nm1);
        float sc2 = __expf(m2 - nm2), sc3 = __expf(m3 - nm3);
        float w0 = __expf(e0 - nm0), w1 = __expf(e1 - nm1);
        float w2 = __expf(e2 - nm2), w3 = __expf(e3 - nm3);
        l0 = l0 * sc0 + wrsum(w0);  l1 = l1 * sc1 + wrsum(w1);
        l2 = l2 * sc2 + wrsum(w2);  l3 = l3 * sc3 + wrsum(w3);
        a0 *= sc0; a1 *= sc1; a2 *= sc2; a3 *= sc3;
        m0 = nm0; m1 = nm1; m2 = nm2; m3 = nm3;
        s_sh[w][lane] = s;
        w_sh[w][lane] = make_float4(w0, w1, w2, w3);
        // wave-private LDS; lockstep wave, no barrier needed
        int cnt4 = (cnt + 3) & ~3;
        for (int j = 0; j < cnt4; j += 4) {
            int sj0 = s_sh[w][j], sj1 = s_sh[w][j + 1], sj2 = s_sh[w][j + 2], sj3 = s_sh[w][j + 3];
            float4 wj0 = w_sh[w][j], wj1 = w_sh[w][j + 1], wj2 = w_sh[w][j + 2], wj3 = w_sh[w][j + 3];
            uint2 u0 = *(const uint2*)(h1b + (size_t)sj0 * 256 + lane * 4);
            uint2 u1 = *(const uint2*)(h1b + (size_t)sj1 * 256 + lane * 4);
            uint2 u2 = *(const uint2*)(h1b + (size_t)sj2 * 256 + lane * 4);
            uint2 u3 = *(const uint2*)(h1b + (size_t)sj3 * 256 + lane * 4);
            a0 += wj0.x * bflo(u0.x); a1 += wj0.y * bfhi(u0.x);
            a2 += wj0.z * bflo(u0.y); a3 += wj0.w * bfhi(u0.y);
            a0 += wj1.x * bflo(u1.x); a1 += wj1.y * bfhi(u1.x);
            a2 += wj1.z * bflo(u1.y); a3 += wj1.w * bfhi(u1.y);
            a0 += wj2.x * bflo(u2.x); a1 += wj2.y * bfhi(u2.x);
            a2 += wj2.z * bflo(u2.y); a3 += wj2.w * bfhi(u2.y);
            a0 += wj3.x * bflo(u3.x); a1 += wj3.y * bfhi(u3.x);
            a2 += wj3.z * bflo(u3.y); a3 += wj3.w * bfhi(u3.y);
        }
    }
    // epilogue: normalize + bias + ELU, write x2b bf16, fold layer-2 scores
    float v0 = a0 / l0 + b1[lane];
    float v1 = a1 / l1 + b1[64 + lane];
    float v2 = a2 / l2 + b1[128 + lane];
    float v3 = a3 / l3 + b1[192 + lane];
    v0 = v0 > 0.f ? v0 : __expf(v0) - 1.f;
    v1 = v1 > 0.f ? v1 : __expf(v1) - 1.f;
    v2 = v2 > 0.f ? v2 : __expf(v2) - 1.f;
    v3 = v3 > 0.f ? v3 : __expf(v3) - 1.f;
    ushort_t* xp = x2b + (size_t)d * 256;
    xp[lane] = f2bf(v0); xp[64 + lane] = f2bf(v1);
    xp[128 + lane] = f2bf(v2); xp[192 + lane] = f2bf(v3);
    float sa = v0 * va[lane] + v1 * va[64 + lane] + v2 * va[128 + lane] + v3 * va[192 + lane];
    float sb = v0 * vb[lane] + v1 * vb[64 + lane] + v2 * vb[128 + lane] + v3 * vb[192 + lane];
    sa = wrsum(sa);
    sb = wrsum(sb);
    if (lane == 0) { ssrc2[d] = sa; sdst2[d] = sb; }
}

// ---------- layer-2 feature aggregation (pre-GEMM, via linearity): x2b 512B rows ----------
__global__ __launch_bounds__(256) void aggx_kernel(const int* __restrict__ rowptr,
                                                   const int* __restrict__ srcbuf,
                                                   const float* __restrict__ ssrc,
                                                   const float* __restrict__ sdst,
                                                   const ushort_t* __restrict__ x2b,
                                                   float* __restrict__ y, int N) {
    __shared__ int   s_sh[4][64];
    __shared__ float w_sh[4][64];
    int lane = threadIdx.x & 63, w = threadIdx.x >> 6;
    int d = blockIdx.x * 4 + w;
    if (d >= N) return;
    int row = rowptr[d], end = rowptr[d + 1];
    float sdv = sdst[d];
    float m = -INFINITY, l = 0.f;
    float a0 = 0.f, a1 = 0.f, a2 = 0.f, a3 = 0.f;
    for (int base = row; base < end; base += 64) {
        int cnt = min(64, end - base);
        bool valid = lane < cnt;
        int s = valid ? srcbuf[base + lane] : 0;
        float e = lrelu(ssrc[s] + sdv);
        if (!valid) e = -INFINITY;
        float nm = fmaxf(m, wrmax(e));
        float sc = __expf(m - nm);
        float wt = __expf(e - nm);
        l = l * sc + wrsum(wt);
        a0 *= sc; a1 *= sc; a2 *= sc; a3 *= sc;
        m = nm;
        s_sh[w][lane] = s;
        w_sh[w][lane] = wt;
        int cnt4 = (cnt + 3) & ~3;
        for (int j = 0; j < cnt4; j += 4) {
            int sj0 = s_sh[w][j], sj1 = s_sh[w][j + 1], sj2 = s_sh[w][j + 2], sj3 = s_sh[w][j + 3];
            float wj0 = w_sh[w][j], wj1 = w_sh[w][j + 1], wj2 = w_sh[w][j + 2], wj3 = w_sh[w][j + 3];
            uint2 u0 = *(const uint2*)(x2b + (size_t)sj0 * 256 + lane * 4);
            uint2 u1 = *(const uint2*)(x2b + (size_t)sj1 * 256 + lane * 4);
            uint2 u2 = *(const uint2*)(x2b + (size_t)sj2 * 256 + lane * 4);
            uint2 u3 = *(const uint2*)(x2b + (size_t)sj3 * 256 + lane * 4);
            a0 += wj0 * bflo(u0.x); a1 += wj0 * bfhi(u0.x);
            a2 += wj0 * bflo(u0.y); a3 += wj0 * bfhi(u0.y);
            a0 += wj1 * bflo(u1.x); a1 += wj1 * bfhi(u1.x);
            a2 += wj1 * bflo(u1.y); a3 += wj1 * bfhi(u1.y);
            a0 += wj2 * bflo(u2.x); a1 += wj2 * bfhi(u2.x);
            a2 += wj2 * bflo(u2.y); a3 += wj2 * bfhi(u2.y);
            a0 += wj3 * bflo(u3.x); a1 += wj3 * bfhi(u3.x);
            a2 += wj3 * bflo(u3.y); a3 += wj3 * bfhi(u3.y);
        }
    }
    float inv = 1.f / l;
    float4 st = make_float4(a0 * inv, a1 * inv, a2 * inv, a3 * inv);
    *(float4*)(y + (size_t)d * 256 + lane * 4) = st;
}

// ---------- final GEMM: (y @ W2 + b2), fused global min ----------
__global__ __launch_bounds__(256) void gemm2min_kernel(const float* __restrict__ y,
                                                       const float* __restrict__ W,
                                                       const float* __restrict__ b2,
                                                       unsigned* __restrict__ minenc, int N) {
    __shared__ float xs[16 * 256];
    int base = blockIdx.x * 16;
    int tid = threadIdx.x;
    const float4* xv = (const float4*)(y + (size_t)base * 256);
    float4* xsv = (float4*)xs;
    #pragma unroll
    for (int i = tid; i < 1024; i += 256) {
        int n = base + (i >> 6);
        xsv[i] = (n < N) ? xv[i] : make_float4(0.f, 0.f, 0.f, 0.f);
    }
    __syncthreads();
    int c = tid & 63, sub = tid >> 6;
    float acc[4] = {0.f, 0.f, 0.f, 0.f};
    for (int k = 0; k < 256; k += 4) {
        float w0 = W[k * 64 + c];
        float w1 = W[(k + 1) * 64 + c];
        float w2 = W[(k + 2) * 64 + c];
        float w3 = W[(k + 3) * 64 + c];
        #pragma unroll
        for (int j = 0; j < 4; j++) {
            float4 xj = *(const float4*)(xs + (sub + 4 * j) * 256 + k);
            acc[j] += xj.x * w0 + xj.y * w1 + xj.z * w2 + xj.w * w3;
        }
    }
    float bc = b2[c];
    float mv = INFINITY;
    #pragma unroll
    for (int j = 0; j < 4; j++) {
        int n = base + sub + 4 * j;
        if (n < N) mv = fminf(mv, acc[j] + bc);
    }
    __shared__ float sm[256];
    sm[tid] = mv;
    __syncthreads();
    if (sub == 0) {
        float v = fminf(fminf(sm[c], sm[64 + c]), fminf(sm[128 + c], sm[192 + c]));
        atomicMin(&minenc[c], fenc(v));
    }
}

__global__ void decode_kernel(const unsigned* __restrict__ minenc, float* __restrict__ out) {
    int d = threadIdx.x;
    if (d < 64) out[d] = fdec(minenc[d]);
}

// ---------- launch ----------
extern "C" void kernel_launch(void* const* d_in, const int* in_sizes, int n_in,
                              void* d_out, int out_size, void* d_ws, size_t ws_size,
                              hipStream_t stream) {
    const float* x      = (const float*)d_in[0];
    const int*   ei     = (const int*)d_in[1];
    const float* W1     = (const float*)d_in[2];
    const float* a_src1 = (const float*)d_in[3];
    const float* a_dst1 = (const float*)d_in[4];
    const float* b1     = (const float*)d_in[5];
    const float* W2     = (const float*)d_in[6];
    const float* a_src2 = (const float*)d_in[7];
    const float* a_dst2 = (const float*)d_in[8];
    const float* b2     = (const float*)d_in[9];
    float* out = (float*)d_out;

    const int N = in_sizes[0] / 128;
    const int E = in_sizes[1] / 2;
    const int Etot = E + N;
    const int Epad = Etot + 64;
    const int M = N + 1;
    const int nchunks = (M + 255) / 256;   // <= 256 for N <= ~65k

    // workspace layout (4-byte words; N divisible by 4 keeps 16B alignment)
    float* ws = (float*)d_ws;
    ushort_t* h1b = (ushort_t*)ws;                     // N*256 bf16 = N*128 words
    ushort_t* x2b = (ushort_t*)(ws + (size_t)N * 128); // N*256 bf16 = N*128 words
    float* y      = ws + (size_t)N * 256;              // N*256 fp32
    float* ssrc1  = y + (size_t)N * 256;               // 4N (16B aligned)
    float* sdst1  = ssrc1 + (size_t)N * 4;             // 4N
    float* ssrc2  = sdst1 + (size_t)N * 4;             // N
    float* sdst2  = ssrc2 + N;                         // N
    float* va     = sdst2 + N;                         // 256
    float* vb     = va + 256;                          // 256
    int*   deg    = (int*)(vb + 256);                  // N+1
    int*   rowptr = deg + M;                           // N+1
    int*   cursor = rowptr + M;                        // N
    int*   csum   = cursor + N;                        // 256
    int*   coff   = csum + 256;                        // 256
    int*   srcbuf = coff + 256;                        // Epad
    unsigned* minenc = (unsigned*)(srcbuf + Epad);     // 64

    hipMemsetAsync(deg, 0, (size_t)M * 4, stream);
    hipMemsetAsync(minenc, 0xFF, 64 * 4, stream);

    int nb16 = (N + 15) / 16;
    int nb4 = (N + 3) / 4;
    gemm1_kernel<<<nb16, 256, 0, stream>>>(x, W1, a_src1, a_dst1, h1b, ssrc1, sdst1, N);

    hist_kernel<<<(Etot + 255) / 256, 256, 0, stream>>>(ei, deg, E, Etot);
    chunksum_kernel<<<nchunks, 256, 0, stream>>>(deg, csum, M);
    scanchunks_kernel<<<1, 256, 0, stream>>>(csum, coff, nchunks);
    rowptr_kernel<<<nchunks, 256, 0, stream>>>(deg, coff, rowptr, cursor, M, N);
    scatter_kernel<<<(Etot + 255) / 256, 256, 0, stream>>>(ei, cursor, srcbuf, E, Etot);

    vab_kernel<<<1, 256, 0, stream>>>(W2, a_src2, a_dst2, va, vb);

    agg1_kernel<<<nb4, 256, 0, stream>>>(rowptr, srcbuf, ssrc1, sdst1, h1b, b1,
                                         va, vb, x2b, ssrc2, sdst2, N);
    aggx_kernel<<<nb4, 256, 0, stream>>>(rowptr, srcbuf, ssrc2, sdst2, x2b, y, N);
    gemm2min_kernel<<<nb16, 256, 0, stream>>>(y, W2, b2, minenc, N);
    decode_kernel<<<1, 64, 0, stream>>>(minenc, out);
}